// Round 4
// baseline (96.048 us; speedup 1.0000x reference)
//
#include <hip/hip_runtime.h>

// ColorReducer: per pixel argmin_k ||p - palette[k]||^2, output palette color,
// planar (B,3,H,W) layout.
//
// CORRECTNESS CONTRACT (R4): ref=np is numpy fp32. Modern numpy's c_einsum
// SOP loop (einsum_sumprod, FMA3/AVX512-dispatched object, count=3 < vstep)
// runs the ascending scalar remainder `accum += a[i]*b[i]`, contracted by the
// compiler into scalar FMAs:
//   dot = fma(b,cb, fma(g,cg, rn(r*cr)))     <- ascending FMA chain, acc=0
// np.sum(pix*pix) / np.sum(pal*pal) are separate ufunc passes over
// materialized squares (no FMA possible), pairwise base case n<8 = forward:
//   pp = ((r*r + g*g) + b*b),  cc = ((cr*cr + cg*cg) + cb*cb)
// d = (pp - 2*dot) + cc  left-to-right; 2*dot exact; argmin first-index
// strict <. __f*_rn intrinsics pin every rounding; no compiler contraction.

constexpr int HW   = 512 * 512;   // pixels per plane (2^18)
constexpr int NCOL = 64;

__global__ __launch_bounds__(256)
void color_reduce_kernel(const float* __restrict__ x,
                         const float* __restrict__ pal,
                         float* __restrict__ out,
                         int npix4) {
  __shared__ float4 coef[NCOL];   // (cr, cg, cb, cc)
  const int tid = threadIdx.x;
  if (tid < NCOL) {
    const float cr = pal[tid * 3 + 0];
    const float cg = pal[tid * 3 + 1];
    const float cb = pal[tid * 3 + 2];
    const float cc = __fadd_rn(__fadd_rn(__fmul_rn(cr, cr), __fmul_rn(cg, cg)),
                               __fmul_rn(cb, cb));
    coef[tid] = make_float4(cr, cg, cb, cc);
  }
  __syncthreads();

  const int i4 = blockIdx.x * blockDim.x + tid;   // group of 4 consecutive pixels
  if (i4 >= npix4) return;
  const int pix = i4 << 2;
  const int b   = pix >> 18;        // / HW
  const int j   = pix & (HW - 1);   // % HW
  const size_t base = (size_t)b * (3 * HW) + j;

  const float4 R  = *(const float4*)(x + base);
  const float4 G  = *(const float4*)(x + base + HW);
  const float4 Bl = *(const float4*)(x + base + 2 * HW);
  const float rr[4] = {R.x, R.y, R.z, R.w};
  const float gg[4] = {G.x, G.y, G.z, G.w};
  const float bb[4] = {Bl.x, Bl.y, Bl.z, Bl.w};

  float pp[4], m1[4];
  int idx[4];
#pragma unroll
  for (int p = 0; p < 4; ++p) {
    pp[p] = __fadd_rn(__fadd_rn(__fmul_rn(rr[p], rr[p]), __fmul_rn(gg[p], gg[p])),
                      __fmul_rn(bb[p], bb[p]));
    m1[p] = 3.4e38f;
    idx[p] = 0;
  }

#pragma unroll 8
  for (int k = 0; k < NCOL; ++k) {
    const float4 cf = coef[k];
#pragma unroll
    for (int p = 0; p < 4; ++p) {
      // numpy einsum ascending-FMA remainder: acc=0; acc=fma(r,cr,acc); ...
      const float dot = __fmaf_rn(bb[p], cf.z,
                         __fmaf_rn(gg[p], cf.y,
                           __fmul_rn(rr[p], cf.x)));
      const float d = __fadd_rn(__fsub_rn(pp[p], __fadd_rn(dot, dot)), cf.w);
      const bool lt = d < m1[p];                 // strict < => first-index tie-break
      m1[p]  = lt ? d : m1[p];
      idx[p] = lt ? k : idx[p];
    }
  }

  const float4 c0 = coef[idx[0]], c1 = coef[idx[1]],
               c2 = coef[idx[2]], c3 = coef[idx[3]];
  *(float4*)(out + base)          = make_float4(c0.x, c1.x, c2.x, c3.x);
  *(float4*)(out + base + HW)     = make_float4(c0.y, c1.y, c2.y, c3.y);
  *(float4*)(out + base + 2 * HW) = make_float4(c0.z, c1.z, c2.z, c3.z);
}

extern "C" void kernel_launch(void* const* d_in, const int* in_sizes, int n_in,
                              void* d_out, int out_size, void* d_ws, size_t ws_size,
                              hipStream_t stream) {
  const float* x   = (const float*)d_in[0];
  const float* pal = (const float*)d_in[1];
  float* out = (float*)d_out;

  const int npix  = in_sizes[0] / 3;   // B*H*W = 2,097,152
  const int npix4 = npix / 4;          // 524,288 threads
  const int block = 256;
  const int grid  = (npix4 + block - 1) / block;
  hipLaunchKernelGGL(color_reduce_kernel, dim3(grid), dim3(block), 0, stream,
                     x, pal, out, npix4);
}